// Round 2
// baseline (4507.830 us; speedup 1.0000x reference)
//
#include <hip/hip_runtime.h>
#include <hip/hip_bf16.h>
#include <cstdint>
#include <cstddef>

#define BB   4
#define SS   1024
#define DD   768
#define HH   4
#define DQ   192
#define DFF  3072
#define NVOC 30522

// -------------------- pack [H,D,DQ] -> [D, H*DQ] --------------------
__global__ __launch_bounds__(256) void k_pack(const float* __restrict__ W,
                                              float* __restrict__ out)
{
  int idx = blockIdx.x * 256 + threadIdx.x;
  if (idx >= DD * DD) return;
  int n = idx % DD, kk = idx / DD;
  int h = n / DQ, dq = n % DQ;
  out[idx] = W[((size_t)h * DD + kk) * DQ + dq];
}

// -------------------- embedding + LayerNorm --------------------
__global__ __launch_bounds__(256) void k_embed_ln(
    const int* __restrict__ ids, const float* __restrict__ tok,
    const float* __restrict__ seg, const float* __restrict__ pos,
    const float* __restrict__ g, const float* __restrict__ bta,
    float* __restrict__ x)
{
  int row = blockIdx.x;           // b*S + s
  int s = row & (SS - 1);
  int id = ids[row];
  int t = threadIdx.x;
  const float* tp = tok + (size_t)id * DD;
  const float* sp = seg + (size_t)id * DD;
  const float* pp = pos + (size_t)s * DD;
  float v[3];
  float sum = 0.f;
#pragma unroll
  for (int j = 0; j < 3; ++j) {
    int d = t + j * 256;
    v[j] = tp[d] + sp[d] + pp[d];
    sum += v[j];
  }
  __shared__ float red[4];
#pragma unroll
  for (int w = 1; w < 64; w <<= 1) sum += __shfl_xor(sum, w);
  int wid = t >> 6, lane = t & 63;
  if (lane == 0) red[wid] = sum;
  __syncthreads();
  float mu = (red[0] + red[1] + red[2] + red[3]) * (1.f / DD);
  float vs = 0.f;
#pragma unroll
  for (int j = 0; j < 3; ++j) { float d2 = v[j] - mu; vs += d2 * d2; }
#pragma unroll
  for (int w = 1; w < 64; w <<= 1) vs += __shfl_xor(vs, w);
  __syncthreads();
  if (lane == 0) red[wid] = vs;
  __syncthreads();
  float var = (red[0] + red[1] + red[2] + red[3]) * (1.f / DD);
  float rstd = rsqrtf(var + 1e-5f);
  float* xr = x + (size_t)row * DD;
#pragma unroll
  for (int j = 0; j < 3; ++j) {
    int d = t + j * 256;
    xr[d] = (v[j] - mu) * rstd * g[d] + bta[d];
  }
}

// -------------------- generic f32 GEMM: C[M,N] = A[M,K] @ B[K,N] + bias --------------------
// 64x64 tile, BK=16, 256 threads, 4x4 per thread. M must be multiple of 64, K of 16.
__global__ __launch_bounds__(256) void k_gemm(
    const float* __restrict__ A, const float* __restrict__ B,
    const float* __restrict__ bias, float* __restrict__ C,
    int M, int N, int K, int relu)
{
  __shared__ float As[16][65];
  __shared__ float Bs[16][64];
  int t = threadIdx.x;
  int tx = t & 15, ty = t >> 4;
  int m0 = blockIdx.y * 64, n0 = blockIdx.x * 64;
  float acc[4][4] = {};
  int ar = t >> 2, ak = (t & 3) << 2;
  int bc = t & 63, br0 = t >> 6;
  for (int k0 = 0; k0 < K; k0 += 16) {
    float4 av = *(const float4*)&A[(size_t)(m0 + ar) * K + k0 + ak];
    As[ak + 0][ar] = av.x; As[ak + 1][ar] = av.y;
    As[ak + 2][ar] = av.z; As[ak + 3][ar] = av.w;
    int nb = n0 + bc;
#pragma unroll
    for (int j = 0; j < 4; ++j) {
      int brr = br0 + j * 4;
      Bs[brr][bc] = (nb < N) ? B[(size_t)(k0 + brr) * N + nb] : 0.f;
    }
    __syncthreads();
#pragma unroll
    for (int kk = 0; kk < 16; ++kk) {
      float a0 = As[kk][ty * 4 + 0], a1 = As[kk][ty * 4 + 1],
            a2 = As[kk][ty * 4 + 2], a3 = As[kk][ty * 4 + 3];
      float b0 = Bs[kk][tx * 4 + 0], b1 = Bs[kk][tx * 4 + 1],
            b2 = Bs[kk][tx * 4 + 2], b3 = Bs[kk][tx * 4 + 3];
      acc[0][0] += a0 * b0; acc[0][1] += a0 * b1; acc[0][2] += a0 * b2; acc[0][3] += a0 * b3;
      acc[1][0] += a1 * b0; acc[1][1] += a1 * b1; acc[1][2] += a1 * b2; acc[1][3] += a1 * b3;
      acc[2][0] += a2 * b0; acc[2][1] += a2 * b1; acc[2][2] += a2 * b2; acc[2][3] += a2 * b3;
      acc[3][0] += a3 * b0; acc[3][1] += a3 * b1; acc[3][2] += a3 * b2; acc[3][3] += a3 * b3;
    }
    __syncthreads();
  }
#pragma unroll
  for (int i = 0; i < 4; ++i) {
    int m = m0 + ty * 4 + i;
#pragma unroll
    for (int j = 0; j < 4; ++j) {
      int n = n0 + tx * 4 + j;
      if (n < N) {
        float vv = acc[i][j] + bias[n];
        if (relu) vv = fmaxf(vv, 0.f);
        C[(size_t)m * N + n] = vv;
      }
    }
  }
}

// -------------------- fused attention (online softmax), one block = (b,h,32 q-rows) --------------------
#define ATK 16
#define DQP 196   // 192 padded to 196: (4g+d)%32 distinct across 8-lane groups

__global__ __launch_bounds__(256) void k_attn(
    const float* __restrict__ q, const float* __restrict__ k,
    const float* __restrict__ v, const unsigned char* __restrict__ mask,
    float* __restrict__ ctx)
{
  __shared__ float Qs[32][DQP];
  __shared__ float Ks[ATK][DQP];
  __shared__ float Vs[ATK][DQP];
  __shared__ float Ps[32][ATK];

  int blk = blockIdx.x;
  int qt = blk & 31;
  int h  = (blk >> 5) & (HH - 1);
  int b  = blk >> 7;
  int q0 = qt * 32;
  int t = threadIdx.x;

  for (int i = t; i < 32 * 48; i += 256) {
    int r = i / 48, c4 = (i % 48) * 4;
    *(float4*)&Qs[r][c4] =
        *(const float4*)&q[((size_t)(b * SS + q0 + r)) * DD + h * DQ + c4];
  }

  int r = t >> 3;           // q row within tile (0..31), owned by one 8-lane group
  int g = t & 7;            // lane within group
  int dq0 = g * 24;         // this lane's 24-wide dq slice
  float m_r = -INFINITY, l_r = 0.f;
  float acc[24];
#pragma unroll
  for (int i = 0; i < 24; ++i) acc[i] = 0.f;

  const unsigned char* mb = mask + (size_t)b * SS * SS + (size_t)(q0 + r) * SS;

  for (int kt = 0; kt < SS / ATK; ++kt) {
    int k0 = kt * ATK;
    __syncthreads();        // previous-iter Vs consumers done; also covers Q load on kt==0
    for (int i = t; i < ATK * 48; i += 256) {
      int rr = i / 48, c4 = (i % 48) * 4;
      size_t gi = ((size_t)(b * SS + k0 + rr)) * DD + h * DQ + c4;
      *(float4*)&Ks[rr][c4] = *(const float4*)&k[gi];
      *(float4*)&Vs[rr][c4] = *(const float4*)&v[gi];
    }
    __syncthreads();

    float sv[2];
#pragma unroll
    for (int jj = 0; jj < 2; ++jj) {
      int kj = g + jj * 8;
      float s = 0.f;
      for (int d = 0; d < DQ; ++d) s += Qs[r][d] * Ks[kj][d];
      s *= (1.f / 32.f);                       // / sqrt(S), S=1024
      if (mb[k0 + kj]) s = -1e9f;              // reference: where(mask, -1e9, scores)
      sv[jj] = s;
    }
    float tmax = fmaxf(sv[0], sv[1]);
#pragma unroll
    for (int w = 1; w < 8; w <<= 1) tmax = fmaxf(tmax, __shfl_xor(tmax, w));
    float mnew = fmaxf(m_r, tmax);
    float alpha = expf(m_r - mnew);            // m_r=-inf first iter -> alpha=0
    float psum = 0.f;
#pragma unroll
    for (int jj = 0; jj < 2; ++jj) {
      float p = expf(sv[jj] - mnew);
      Ps[r][g + jj * 8] = p;                   // row owned by this wave's 8-lane group
      psum += p;
    }
#pragma unroll
    for (int w = 1; w < 8; w <<= 1) psum += __shfl_xor(psum, w);
    l_r = l_r * alpha + psum;
    m_r = mnew;
#pragma unroll
    for (int i = 0; i < 24; ++i) acc[i] *= alpha;
    for (int kj = 0; kj < ATK; ++kj) {
      float p = Ps[r][kj];                     // same-wave LDS, program order OK
#pragma unroll
      for (int i = 0; i < 24; ++i) acc[i] += p * Vs[kj][dq0 + i];
    }
  }
  float linv = 1.f / l_r;
  float* cr = ctx + ((size_t)(b * SS + q0 + r)) * DD + h * DQ + dq0;
#pragma unroll
  for (int i = 0; i < 24; ++i) cr[i] = acc[i] * linv;
}

// -------------------- cls head: ff[:,0,:] @ Wcls + bcls --------------------
__global__ void k_cls(const float* __restrict__ ff, const float* __restrict__ Wc,
                      const float* __restrict__ bc, float* __restrict__ out)
{
  int t = threadIdx.x;        // 64 threads, 8 outputs x 8 lanes
  int o = t >> 3, l8 = t & 7;
  int b = o >> 1, c = o & 1;
  float s = 0.f;
  for (int d = l8; d < DD; d += 8)
    s += ff[(size_t)(b * SS) * DD + d] * Wc[d * 2 + c];
#pragma unroll
  for (int w = 1; w < 8; w <<= 1) s += __shfl_xor(s, w);
  if (l8 == 0) out[o] = s + bc[c];
}

extern "C" void kernel_launch(void* const* d_in, const int* in_sizes, int n_in,
                              void* d_out, int out_size, void* d_ws, size_t ws_size,
                              hipStream_t stream)
{
  const int*           ids  = (const int*)d_in[0];
  const unsigned char* mask = (const unsigned char*)d_in[1];
  const float* tok  = (const float*)d_in[2];
  const float* seg  = (const float*)d_in[3];
  const float* pos  = (const float*)d_in[4];
  const float* ln_g = (const float*)d_in[5];
  const float* ln_b = (const float*)d_in[6];
  const float* Wq   = (const float*)d_in[7];
  const float* bq   = (const float*)d_in[8];
  const float* Wk   = (const float*)d_in[9];
  const float* bk   = (const float*)d_in[10];
  const float* Wv   = (const float*)d_in[11];
  const float* bv   = (const float*)d_in[12];
  const float* Wo   = (const float*)d_in[13];
  const float* bo   = (const float*)d_in[14];
  const float* W1   = (const float*)d_in[15];
  const float* b1   = (const float*)d_in[16];
  const float* W2   = (const float*)d_in[17];
  const float* b2   = (const float*)d_in[18];
  const float* Wtok = (const float*)d_in[19];
  const float* btok = (const float*)d_in[20];
  const float* Wcls = (const float*)d_in[21];
  const float* bcls = (const float*)d_in[22];

  // workspace layout (floats); aliasing respects lifetimes:
  //   wqp|wkp|wvp (1.77M) | x (3.15M) | q|k|v|ctx (12.58M, later reused as ff1) | att (3.15M)
  //   ff aliases x. Total 20,643,840 floats = 82.6 MB.
  float* ws  = (float*)d_ws;
  float* wqp = ws;
  float* wkp = wqp + 589824;
  float* wvp = wkp + 589824;
  float* x   = wvp + 589824;
  float* q   = x + 3145728;
  float* kk  = q + 3145728;
  float* vv  = kk + 3145728;
  float* ctx = vv + 3145728;
  float* att = ctx + 3145728;
  float* ff1 = q;    // aliases q..ctx (12,582,912 floats) after attention is done
  float* ff  = x;    // aliases x after QKV is done

  float* cls    = (float*)d_out;
  float* tokout = (float*)d_out + 8;

  // 1. pack per-head projection weights to [D, H*DQ]
  k_pack<<<2304, 256, 0, stream>>>(Wq, wqp);
  k_pack<<<2304, 256, 0, stream>>>(Wk, wkp);
  k_pack<<<2304, 256, 0, stream>>>(Wv, wvp);

  // 2. embeddings + LayerNorm -> x [4096, 768]
  k_embed_ln<<<BB * SS, 256, 0, stream>>>(ids, tok, seg, pos, ln_g, ln_b, x);

  // 3. Q,K,V projections  [4096,768] @ [768,768] + bias (flat [H*DQ] matches columns)
  dim3 g64(12, 64);
  k_gemm<<<g64, 256, 0, stream>>>(x, wqp, bq, q,  BB * SS, DD, DD, 0);
  k_gemm<<<g64, 256, 0, stream>>>(x, wkp, bk, kk, BB * SS, DD, DD, 0);
  k_gemm<<<g64, 256, 0, stream>>>(x, wvp, bv, vv, BB * SS, DD, DD, 0);

  // 4. attention -> ctx [4096, 768] (heads concatenated)
  k_attn<<<BB * HH * (SS / 32), 256, 0, stream>>>(q, kk, vv, mask, ctx);

  // 5. output projection
  k_gemm<<<g64, 256, 0, stream>>>(ctx, Wo, bo, att, BB * SS, DD, DD, 0);

  // 6. FFN
  k_gemm<<<dim3(DFF / 64, 64), 256, 0, stream>>>(att, W1, b1, ff1, BB * SS, DFF, DD, 1);
  k_gemm<<<g64, 256, 0, stream>>>(ff1, W2, b2, ff, BB * SS, DD, DFF, 0);

  // 7. cls head (reads ff rows b*S)
  k_cls<<<1, 64, 0, stream>>>(ff, Wcls, bcls, cls);

  // 8. vocab projection -> d_out+8  [4096, 30522]
  k_gemm<<<dim3((NVOC + 63) / 64, 64), 256, 0, stream>>>(ff, Wtok, btok, tokout,
                                                         BB * SS, NVOC, DD, 0);
}

// Round 3
// 1860.842 us; speedup vs baseline: 2.4225x; 2.4225x over previous
//
#include <hip/hip_runtime.h>
#include <hip/hip_bf16.h>
#include <cstdint>
#include <cstddef>

#define BB   4
#define SS   1024
#define DD   768
#define HH   4
#define DQ   192
#define DFF  3072
#define NVOC 30522
#define NPAD 30592   // 239 * 128
#define NT   239

typedef __attribute__((ext_vector_type(8))) short bf16x8;
typedef __attribute__((ext_vector_type(4))) float f32x4;
#define AS1 __attribute__((address_space(1)))
#define AS3 __attribute__((address_space(3)))

// -------------------- pack [H,D,DQ] -> [D, H*DQ] --------------------
__global__ __launch_bounds__(256) void k_pack(const float* __restrict__ W,
                                              float* __restrict__ out)
{
  int idx = blockIdx.x * 256 + threadIdx.x;
  if (idx >= DD * DD) return;
  int n = idx % DD, kk = idx / DD;
  int h = n / DQ, dq = n % DQ;
  out[idx] = W[((size_t)h * DD + kk) * DQ + dq];
}

// -------------------- embedding + LayerNorm --------------------
__global__ __launch_bounds__(256) void k_embed_ln(
    const int* __restrict__ ids, const float* __restrict__ tok,
    const float* __restrict__ seg, const float* __restrict__ pos,
    const float* __restrict__ g, const float* __restrict__ bta,
    float* __restrict__ x)
{
  int row = blockIdx.x;           // b*S + s
  int s = row & (SS - 1);
  int id = ids[row];
  int t = threadIdx.x;
  const float* tp = tok + (size_t)id * DD;
  const float* sp = seg + (size_t)id * DD;
  const float* pp = pos + (size_t)s * DD;
  float v[3];
  float sum = 0.f;
#pragma unroll
  for (int j = 0; j < 3; ++j) {
    int d = t + j * 256;
    v[j] = tp[d] + sp[d] + pp[d];
    sum += v[j];
  }
  __shared__ float red[4];
#pragma unroll
  for (int w = 1; w < 64; w <<= 1) sum += __shfl_xor(sum, w);
  int wid = t >> 6, lane = t & 63;
  if (lane == 0) red[wid] = sum;
  __syncthreads();
  float mu = (red[0] + red[1] + red[2] + red[3]) * (1.f / DD);
  float vs = 0.f;
#pragma unroll
  for (int j = 0; j < 3; ++j) { float d2 = v[j] - mu; vs += d2 * d2; }
#pragma unroll
  for (int w = 1; w < 64; w <<= 1) vs += __shfl_xor(vs, w);
  __syncthreads();
  if (lane == 0) red[wid] = vs;
  __syncthreads();
  float var = (red[0] + red[1] + red[2] + red[3]) * (1.f / DD);
  float rstd = rsqrtf(var + 1e-5f);
  float* xr = x + (size_t)row * DD;
#pragma unroll
  for (int j = 0; j < 3; ++j) {
    int d = t + j * 256;
    xr[d] = (v[j] - mu) * rstd * g[d] + bta[d];
  }
}

// -------------------- generic f32 GEMM (kept for sub-dominant GEMMs) --------------------
__global__ __launch_bounds__(256) void k_gemm(
    const float* __restrict__ A, const float* __restrict__ B,
    const float* __restrict__ bias, float* __restrict__ C,
    int M, int N, int K, int relu)
{
  __shared__ float As[16][65];
  __shared__ float Bs[16][64];
  int t = threadIdx.x;
  int tx = t & 15, ty = t >> 4;
  int m0 = blockIdx.y * 64, n0 = blockIdx.x * 64;
  float acc[4][4] = {};
  int ar = t >> 2, ak = (t & 3) << 2;
  int bc = t & 63, br0 = t >> 6;
  for (int k0 = 0; k0 < K; k0 += 16) {
    float4 av = *(const float4*)&A[(size_t)(m0 + ar) * K + k0 + ak];
    As[ak + 0][ar] = av.x; As[ak + 1][ar] = av.y;
    As[ak + 2][ar] = av.z; As[ak + 3][ar] = av.w;
    int nb = n0 + bc;
#pragma unroll
    for (int j = 0; j < 4; ++j) {
      int brr = br0 + j * 4;
      Bs[brr][bc] = (nb < N) ? B[(size_t)(k0 + brr) * N + nb] : 0.f;
    }
    __syncthreads();
#pragma unroll
    for (int kk = 0; kk < 16; ++kk) {
      float a0 = As[kk][ty * 4 + 0], a1 = As[kk][ty * 4 + 1],
            a2 = As[kk][ty * 4 + 2], a3 = As[kk][ty * 4 + 3];
      float b0 = Bs[kk][tx * 4 + 0], b1 = Bs[kk][tx * 4 + 1],
            b2 = Bs[kk][tx * 4 + 2], b3 = Bs[kk][tx * 4 + 3];
      acc[0][0] += a0 * b0; acc[0][1] += a0 * b1; acc[0][2] += a0 * b2; acc[0][3] += a0 * b3;
      acc[1][0] += a1 * b0; acc[1][1] += a1 * b1; acc[1][2] += a1 * b2; acc[1][3] += a1 * b3;
      acc[2][0] += a2 * b0; acc[2][1] += a2 * b1; acc[2][2] += a2 * b2; acc[2][3] += a2 * b3;
      acc[3][0] += a3 * b0; acc[3][1] += a3 * b1; acc[3][2] += a3 * b2; acc[3][3] += a3 * b3;
    }
    __syncthreads();
  }
#pragma unroll
  for (int i = 0; i < 4; ++i) {
    int m = m0 + ty * 4 + i;
#pragma unroll
    for (int j = 0; j < 4; ++j) {
      int n = n0 + tx * 4 + j;
      if (n < N) {
        float vv = acc[i][j] + bias[n];
        if (relu) vv = fmaxf(vv, 0.f);
        C[(size_t)m * N + n] = vv;
      }
    }
  }
}

// -------------------- fused attention (online softmax) --------------------
#define ATK 16
#define DQP 196

__global__ __launch_bounds__(256) void k_attn(
    const float* __restrict__ q, const float* __restrict__ k,
    const float* __restrict__ v, const unsigned char* __restrict__ mask,
    float* __restrict__ ctx)
{
  __shared__ float Qs[32][DQP];
  __shared__ float Ks[ATK][DQP];
  __shared__ float Vs[ATK][DQP];
  __shared__ float Ps[32][ATK];

  int blk = blockIdx.x;
  int qt = blk & 31;
  int h  = (blk >> 5) & (HH - 1);
  int b  = blk >> 7;
  int q0 = qt * 32;
  int t = threadIdx.x;

  for (int i = t; i < 32 * 48; i += 256) {
    int r = i / 48, c4 = (i % 48) * 4;
    *(float4*)&Qs[r][c4] =
        *(const float4*)&q[((size_t)(b * SS + q0 + r)) * DD + h * DQ + c4];
  }

  int r = t >> 3;
  int g = t & 7;
  int dq0 = g * 24;
  float m_r = -INFINITY, l_r = 0.f;
  float acc[24];
#pragma unroll
  for (int i = 0; i < 24; ++i) acc[i] = 0.f;

  const unsigned char* mb = mask + (size_t)b * SS * SS + (size_t)(q0 + r) * SS;

  for (int kt = 0; kt < SS / ATK; ++kt) {
    int k0 = kt * ATK;
    __syncthreads();
    for (int i = t; i < ATK * 48; i += 256) {
      int rr = i / 48, c4 = (i % 48) * 4;
      size_t gi = ((size_t)(b * SS + k0 + rr)) * DD + h * DQ + c4;
      *(float4*)&Ks[rr][c4] = *(const float4*)&k[gi];
      *(float4*)&Vs[rr][c4] = *(const float4*)&v[gi];
    }
    __syncthreads();

    float sv[2];
#pragma unroll
    for (int jj = 0; jj < 2; ++jj) {
      int kj = g + jj * 8;
      float s = 0.f;
      for (int d = 0; d < DQ; ++d) s += Qs[r][d] * Ks[kj][d];
      s *= (1.f / 32.f);
      if (mb[k0 + kj]) s = -1e9f;
      sv[jj] = s;
    }
    float tmax = fmaxf(sv[0], sv[1]);
#pragma unroll
    for (int w = 1; w < 8; w <<= 1) tmax = fmaxf(tmax, __shfl_xor(tmax, w));
    float mnew = fmaxf(m_r, tmax);
    float alpha = expf(m_r - mnew);
    float psum = 0.f;
#pragma unroll
    for (int jj = 0; jj < 2; ++jj) {
      float p = expf(sv[jj] - mnew);
      Ps[r][g + jj * 8] = p;
      psum += p;
    }
#pragma unroll
    for (int w = 1; w < 8; w <<= 1) psum += __shfl_xor(psum, w);
    l_r = l_r * alpha + psum;
    m_r = mnew;
#pragma unroll
    for (int i = 0; i < 24; ++i) acc[i] *= alpha;
    for (int kj = 0; kj < ATK; ++kj) {
      float p = Ps[r][kj];
#pragma unroll
      for (int i = 0; i < 24; ++i) acc[i] += p * Vs[kj][dq0 + i];
    }
  }
  float linv = 1.f / l_r;
  float* cr = ctx + ((size_t)(b * SS + q0 + r)) * DD + h * DQ + dq0;
#pragma unroll
  for (int i = 0; i < 24; ++i) cr[i] = acc[i] * linv;
}

// -------------------- cls head --------------------
__global__ void k_cls(const float* __restrict__ ff, const float* __restrict__ Wc,
                      const float* __restrict__ bc, float* __restrict__ out)
{
  int t = threadIdx.x;
  int o = t >> 3, l8 = t & 7;
  int b = o >> 1, c = o & 1;
  float s = 0.f;
  for (int d = l8; d < DD; d += 8)
    s += ff[(size_t)(b * SS) * DD + d] * Wc[d * 2 + c];
#pragma unroll
  for (int w = 1; w < 8; w <<= 1) s += __shfl_xor(s, w);
  if (l8 == 0) out[o] = s + bc[c];
}

// -------------------- f32 -> bf16 convert (ff) --------------------
__global__ __launch_bounds__(256) void k_cvt(const float* __restrict__ in,
                                             __hip_bfloat16* __restrict__ out)
{
  int i = (blockIdx.x * 256 + threadIdx.x) * 4;   // n is multiple of 4
  float4 v = *(const float4*)&in[i];
  out[i + 0] = __float2bfloat16(v.x);
  out[i + 1] = __float2bfloat16(v.y);
  out[i + 2] = __float2bfloat16(v.z);
  out[i + 3] = __float2bfloat16(v.w);
}

// -------------------- Wtok [768][30522] f32 -> Bt [30592][768] bf16 (transposed) ------
__global__ __launch_bounds__(256) void k_transpose_bf16(
    const float* __restrict__ W, __hip_bfloat16* __restrict__ Bt)
{
  __shared__ float tile[32][33];
  int n0 = blockIdx.x * 32, k0 = blockIdx.y * 32;
  int tx = threadIdx.x & 31, ty = threadIdx.x >> 5;   // 32 x 8
#pragma unroll
  for (int j = 0; j < 4; ++j) {
    int kk = ty + j * 8;
    tile[kk][tx] = (n0 + tx < NVOC) ? W[(size_t)(k0 + kk) * NVOC + n0 + tx] : 0.f;
  }
  __syncthreads();
#pragma unroll
  for (int j = 0; j < 4; ++j) {
    int r = ty + j * 8;                 // local n
    Bt[(size_t)(n0 + r) * DD + k0 + tx] = __float2bfloat16(tile[tx][r]);
  }
}

// -------------------- bf16 MFMA GEMM: C[4096,30522] = A[4096,768] @ Bt^T + bias ------
// 128x128 tile, BK=64, 4 waves (2x2), 16x16x32 MFMA, global_load_lds width 16.
__global__ __launch_bounds__(256) void k_gemm_bf16(
    const short* __restrict__ A,    // [4096][768] bf16
    const short* __restrict__ Bt,   // [30592][768] bf16 (row = output col)
    const float* __restrict__ bias, float* __restrict__ C)
{
  __shared__ alignas(16) short As[128 * 64];
  __shared__ alignas(16) short Bs[128 * 64];

  // XCD-aware swizzle: 7648 blocks, 8 XCDs -> chunk of 956 = 239 n-tiles x 4 m-tiles.
  // Within a chunk: 4 consecutive blocks share one B-tile (L2 hit), A rows cycle 4-wide.
  int bid = blockIdx.x;
  int xcd = bid & 7;
  int c   = bid >> 3;           // 0..955
  int tm  = xcd * 4 + (c & 3);  // 0..31
  int tn  = c >> 2;             // 0..238
  int m0 = tm * 128, n0 = tn * 128;

  int t = threadIdx.x;
  int w = t >> 6, l = t & 63;
  int lr = l >> 3, lc = l & 7;        // staging: 8 rows x 8 col-blocks per chunk
  int fr = l & 15, fq = l >> 4;       // fragment lane decode
  int wr = w >> 1, wc = w & 1;        // wave -> 64x64 quadrant

  f32x4 acc[4][4];
#pragma unroll
  for (int i = 0; i < 4; ++i)
#pragma unroll
    for (int j = 0; j < 4; ++j)
      acc[i][j] = (f32x4){0.f, 0.f, 0.f, 0.f};

  for (int k0 = 0; k0 < DD; k0 += 64) {
#pragma unroll
    for (int i = 0; i < 4; ++i) {
      int chunk = i * 4 + w;          // 0..15, wave-uniform
      int row = chunk * 8 + lr;       // 0..127
      const short* gA = &A[(size_t)(m0 + row) * DD + k0 + lc * 8];
      const short* gB = &Bt[(size_t)(n0 + row) * DD + k0 + lc * 8];
      __builtin_amdgcn_global_load_lds((const AS1 void*)gA, (AS3 void*)&As[chunk * 512], 16, 0, 0);
      __builtin_amdgcn_global_load_lds((const AS1 void*)gB, (AS3 void*)&Bs[chunk * 512], 16, 0, 0);
    }
    __syncthreads();                  // drains vmcnt, data visible
#pragma unroll
    for (int ks = 0; ks < 2; ++ks) {
      bf16x8 af[4], bfr[4];
#pragma unroll
      for (int mi = 0; mi < 4; ++mi)
        af[mi] = *(const bf16x8*)&As[(wr * 64 + mi * 16 + fr) * 64 + ks * 32 + fq * 8];
#pragma unroll
      for (int nj = 0; nj < 4; ++nj)
        bfr[nj] = *(const bf16x8*)&Bs[(wc * 64 + nj * 16 + fr) * 64 + ks * 32 + fq * 8];
#pragma unroll
      for (int mi = 0; mi < 4; ++mi)
#pragma unroll
        for (int nj = 0; nj < 4; ++nj)
          acc[mi][nj] = __builtin_amdgcn_mfma_f32_16x16x32_bf16(af[mi], bfr[nj], acc[mi][nj], 0, 0, 0);
    }
    __syncthreads();
  }

  // epilogue: C/D layout col = lane&15, row = (lane>>4)*4 + reg
#pragma unroll
  for (int nj = 0; nj < 4; ++nj) {
    int col = n0 + wc * 64 + nj * 16 + fr;
    if (col < NVOC) {
      float bv = bias[col];
#pragma unroll
      for (int mi = 0; mi < 4; ++mi) {
#pragma unroll
        for (int rg = 0; rg < 4; ++rg) {
          int row = m0 + wr * 64 + mi * 16 + fq * 4 + rg;
          C[(size_t)row * NVOC + col] = acc[mi][nj][rg] + bv;
        }
      }
    }
  }
}

extern "C" void kernel_launch(void* const* d_in, const int* in_sizes, int n_in,
                              void* d_out, int out_size, void* d_ws, size_t ws_size,
                              hipStream_t stream)
{
  const int*           ids  = (const int*)d_in[0];
  const unsigned char* mask = (const unsigned char*)d_in[1];
  const float* tok  = (const float*)d_in[2];
  const float* seg  = (const float*)d_in[3];
  const float* pos  = (const float*)d_in[4];
  const float* ln_g = (const float*)d_in[5];
  const float* ln_b = (const float*)d_in[6];
  const float* Wq   = (const float*)d_in[7];
  const float* bq   = (const float*)d_in[8];
  const float* Wk   = (const float*)d_in[9];
  const float* bk   = (const float*)d_in[10];
  const float* Wv   = (const float*)d_in[11];
  const float* bv   = (const float*)d_in[12];
  const float* Wo   = (const float*)d_in[13];
  const float* bo   = (const float*)d_in[14];
  const float* W1   = (const float*)d_in[15];
  const float* b1   = (const float*)d_in[16];
  const float* W2   = (const float*)d_in[17];
  const float* b2   = (const float*)d_in[18];
  const float* Wtok = (const float*)d_in[19];
  const float* btok = (const float*)d_in[20];
  const float* Wcls = (const float*)d_in[21];
  const float* bcls = (const float*)d_in[22];

  // workspace layout (floats), 82.6 MB total, aliasing respects lifetimes.
  float* ws  = (float*)d_ws;
  float* wqp = ws;
  float* wkp = wqp + 589824;
  float* wvp = wkp + 589824;
  float* x   = wvp + 589824;
  float* q   = x + 3145728;
  float* kk  = q + 3145728;
  float* vv  = kk + 3145728;
  float* ctx = vv + 3145728;
  float* att = ctx + 3145728;
  float* ff1 = q;    // [4096][3072] f32, aliases q..ctx, live between W1 and W2 GEMMs
  float* ff  = x;    // aliases x after QKV done
  // post-W2 aliases:
  __hip_bfloat16* ffb = (__hip_bfloat16*)att;  // 6.3 MB in att's 12.6 MB
  __hip_bfloat16* Bt  = (__hip_bfloat16*)q;    // 47.0 MB in q..ctx's 50.3 MB

  float* cls    = (float*)d_out;
  float* tokout = (float*)d_out + 8;

  // 1. pack per-head projection weights
  k_pack<<<2304, 256, 0, stream>>>(Wq, wqp);
  k_pack<<<2304, 256, 0, stream>>>(Wk, wkp);
  k_pack<<<2304, 256, 0, stream>>>(Wv, wvp);

  // 2. embeddings + LayerNorm
  k_embed_ln<<<BB * SS, 256, 0, stream>>>(ids, tok, seg, pos, ln_g, ln_b, x);

  // 3. QKV projections (f32 — accuracy chain for cls head)
  dim3 g64(12, 64);
  k_gemm<<<g64, 256, 0, stream>>>(x, wqp, bq, q,  BB * SS, DD, DD, 0);
  k_gemm<<<g64, 256, 0, stream>>>(x, wkp, bk, kk, BB * SS, DD, DD, 0);
  k_gemm<<<g64, 256, 0, stream>>>(x, wvp, bv, vv, BB * SS, DD, DD, 0);

  // 4. attention
  k_attn<<<BB * HH * (SS / 32), 256, 0, stream>>>(q, kk, vv, mask, ctx);

  // 5. output projection
  k_gemm<<<g64, 256, 0, stream>>>(ctx, Wo, bo, att, BB * SS, DD, DD, 0);

  // 6. FFN (f32)
  k_gemm<<<dim3(DFF / 64, 64), 256, 0, stream>>>(att, W1, b1, ff1, BB * SS, DFF, DD, 1);
  k_gemm<<<g64, 256, 0, stream>>>(ff1, W2, b2, ff, BB * SS, DD, DFF, 0);

  // 7. cls head (f32 path, tight threshold)
  k_cls<<<1, 64, 0, stream>>>(ff, Wcls, bcls, cls);

  // 8. vocab projection in bf16 MFMA
  k_cvt<<<3145728 / 1024, 256, 0, stream>>>(ff, ffb);                       // ff -> bf16
  k_transpose_bf16<<<dim3(NPAD / 32, DD / 32), 256, 0, stream>>>(Wtok, Bt); // Wtok -> Bt
  k_gemm_bf16<<<32 * NT, 256, 0, stream>>>((const short*)ffb, (const short*)Bt,
                                           btok, tokout);
}

// Round 5
// 1374.819 us; speedup vs baseline: 3.2789x; 1.3535x over previous
//
#include <hip/hip_runtime.h>
#include <hip/hip_bf16.h>
#include <cstdint>
#include <cstddef>

#define BB   4
#define SS   1024
#define DD   768
#define HH   4
#define DQ   192
#define DFF  3072
#define NVOC 30522
#define NPAD 30592   // 239 * 128

typedef __attribute__((ext_vector_type(8))) short bf16x8;
typedef __attribute__((ext_vector_type(4))) float f32x4;
#define AS1 __attribute__((address_space(1)))
#define AS3 __attribute__((address_space(3)))

static __device__ __forceinline__ float bf2f(short s) {
  union { unsigned int u; float f; } v; v.u = ((unsigned int)(unsigned short)s) << 16; return v.f;
}
static __device__ __forceinline__ short f2bf(float f) {
  union { float f; unsigned int u; } v; v.f = f;
  unsigned int r = v.u + 0x7FFFu + ((v.u >> 16) & 1u);   // round-to-nearest-even
  if ((v.u & 0x7F800000u) == 0x7F800000u) r = v.u;       // inf/nan: truncate
  return (short)(r >> 16);
}

// ==================== embedding + LayerNorm -> xb (bf16), x0 (f32 rows s=0) ============
__global__ __launch_bounds__(256) void k_embed_ln(
    const int* __restrict__ ids, const float* __restrict__ tok,
    const float* __restrict__ seg, const float* __restrict__ pos,
    const float* __restrict__ g, const float* __restrict__ bta,
    short* __restrict__ xb, float* __restrict__ x0)
{
  int row = blockIdx.x;           // b*S + s
  int s = row & (SS - 1);
  int id = ids[row];
  int t = threadIdx.x;
  const float* tp = tok + (size_t)id * DD;
  const float* sp = seg + (size_t)id * DD;
  const float* pp = pos + (size_t)s * DD;
  float v[3];
  float sum = 0.f;
#pragma unroll
  for (int j = 0; j < 3; ++j) {
    int d = t + j * 256;
    v[j] = tp[d] + sp[d] + pp[d];
    sum += v[j];
  }
  __shared__ float red[4];
#pragma unroll
  for (int w = 1; w < 64; w <<= 1) sum += __shfl_xor(sum, w);
  int wid = t >> 6, lane = t & 63;
  if (lane == 0) red[wid] = sum;
  __syncthreads();
  float mu = (red[0] + red[1] + red[2] + red[3]) * (1.f / DD);
  float vs = 0.f;
#pragma unroll
  for (int j = 0; j < 3; ++j) { float d2 = v[j] - mu; vs += d2 * d2; }
#pragma unroll
  for (int w = 1; w < 64; w <<= 1) vs += __shfl_xor(vs, w);
  __syncthreads();
  if (lane == 0) red[wid] = vs;
  __syncthreads();
  float var = (red[0] + red[1] + red[2] + red[3]) * (1.f / DD);
  float rstd = rsqrtf(var + 1e-5f);
#pragma unroll
  for (int j = 0; j < 3; ++j) {
    int d = t + j * 256;
    float val = (v[j] - mu) * rstd * g[d] + bta[d];
    xb[(size_t)row * DD + d] = f2bf(val);
    if (s == 0) x0[(row >> 10) * DD + d] = val;
  }
}

// ==================== pack QKV weights -> Btqkv[2304][768] bf16 ====================
__global__ __launch_bounds__(256) void k_packqkv(
    const float* __restrict__ Wq, const float* __restrict__ Wk,
    const float* __restrict__ Wv, short* __restrict__ Bt)
{
  __shared__ float tile[32][33];
  int dq0 = blockIdx.x * 32;            // 0..160 within head
  int k0  = blockIdx.y * 32;
  int z   = blockIdx.z;                 // mat*4 + h
  int mat = z >> 2, h = z & 3;
  const float* W = mat == 0 ? Wq : (mat == 1 ? Wk : Wv);
  int tx = threadIdx.x & 31, ty = threadIdx.x >> 5;
#pragma unroll
  for (int j = 0; j < 4; ++j) {
    int kk = ty + j * 8;
    tile[kk][tx] = W[((size_t)h * DD + k0 + kk) * DQ + dq0 + tx];
  }
  __syncthreads();
#pragma unroll
  for (int j = 0; j < 4; ++j) {
    int r = ty + j * 8;                 // local dq
    Bt[(size_t)(mat * DD + h * DQ + dq0 + r) * DD + k0 + tx] = f2bf(tile[tx][r]);
  }
}

__global__ void k_bpack(const float* __restrict__ bq, const float* __restrict__ bk,
                        const float* __restrict__ bv, float* __restrict__ out)
{
  int t = blockIdx.x * 256 + threadIdx.x;
  if (t >= 3 * DD) return;
  out[t] = (t < DD) ? bq[t] : (t < 2 * DD ? bk[t - DD] : bv[t - 2 * DD]);
}

// ==================== generic f32[K][N] -> bf16 Bt[Npad][K] transpose ==============
__global__ __launch_bounds__(256) void k_wtrans(
    const float* __restrict__ W, short* __restrict__ Bt, int N, int K)
{
  __shared__ float tile[32][33];
  int n0 = blockIdx.x * 32, k0 = blockIdx.y * 32;
  int tx = threadIdx.x & 31, ty = threadIdx.x >> 5;
#pragma unroll
  for (int j = 0; j < 4; ++j) {
    int kk = ty + j * 8;
    tile[kk][tx] = (n0 + tx < N) ? W[(size_t)(k0 + kk) * N + n0 + tx] : 0.f;
  }
  __syncthreads();
#pragma unroll
  for (int j = 0; j < 4; ++j) {
    int r = ty + j * 8;
    Bt[(size_t)(n0 + r) * K + k0 + tx] = f2bf(tile[tx][r]);
  }
}

// ==================== V section of qkvb -> vt[768][4096] bf16 ======================
__global__ __launch_bounds__(256) void k_vtrans(
    const short* __restrict__ qkvb, short* __restrict__ vt)
{
  __shared__ short tile[32][33];
  int s0 = blockIdx.x * 32, d0 = blockIdx.y * 32;
  int tx = threadIdx.x & 31, ty = threadIdx.x >> 5;
#pragma unroll
  for (int j = 0; j < 4; ++j) {
    int kk = ty + j * 8;
    tile[kk][tx] = qkvb[(size_t)(s0 + kk) * 2304 + 2 * DD + d0 + tx];
  }
  __syncthreads();
#pragma unroll
  for (int j = 0; j < 4; ++j) {
    int r = ty + j * 8;
    vt[(size_t)(d0 + r) * (BB * SS) + s0 + tx] = tile[tx][r];
  }
}

// ==================== bf16 MFMA GEMM (M=4096), 128x128 tile, BK=64 =================
template <int OUTBF, int RELU>
__global__ __launch_bounds__(256) void k_gemm_bf16(
    const short* __restrict__ A,    // [4096][K] bf16
    const short* __restrict__ Bt,   // [Ntiles*128][K] bf16 (row = output col)
    const float* __restrict__ bias, void* __restrict__ Cout,
    int N, int K, int NT)
{
  __shared__ alignas(16) short As[128 * 64];
  __shared__ alignas(16) short Bs[128 * 64];

  int bid = blockIdx.x;
  int xcd = bid & 7;
  int c   = bid >> 3;
  int tm  = xcd * 4 + (c & 3);  // 0..31
  int tn  = c >> 2;             // 0..NT-1
  int m0 = tm * 128, n0 = tn * 128;

  int t = threadIdx.x;
  int w = t >> 6, l = t & 63;
  int lr = l >> 3, lc = l & 7;
  int fr = l & 15, fq = l >> 4;
  int wr = w >> 1, wc = w & 1;

  f32x4 acc[4][4];
#pragma unroll
  for (int i = 0; i < 4; ++i)
#pragma unroll
    for (int j = 0; j < 4; ++j)
      acc[i][j] = (f32x4){0.f, 0.f, 0.f, 0.f};

  for (int k0 = 0; k0 < K; k0 += 64) {
#pragma unroll
    for (int i = 0; i < 4; ++i) {
      int chunk = i * 4 + w;
      int row = chunk * 8 + lr;
      const short* gA = &A[(size_t)(m0 + row) * K + k0 + lc * 8];
      const short* gB = &Bt[(size_t)(n0 + row) * K + k0 + lc * 8];
      __builtin_amdgcn_global_load_lds((const AS1 void*)gA, (AS3 void*)&As[chunk * 512], 16, 0, 0);
      __builtin_amdgcn_global_load_lds((const AS1 void*)gB, (AS3 void*)&Bs[chunk * 512], 16, 0, 0);
    }
    __syncthreads();
#pragma unroll
    for (int ks = 0; ks < 2; ++ks) {
      bf16x8 af[4], bfr[4];
#pragma unroll
      for (int mi = 0; mi < 4; ++mi)
        af[mi] = *(const bf16x8*)&As[(wr * 64 + mi * 16 + fr) * 64 + ks * 32 + fq * 8];
#pragma unroll
      for (int nj = 0; nj < 4; ++nj)
        bfr[nj] = *(const bf16x8*)&Bs[(wc * 64 + nj * 16 + fr) * 64 + ks * 32 + fq * 8];
#pragma unroll
      for (int mi = 0; mi < 4; ++mi)
#pragma unroll
        for (int nj = 0; nj < 4; ++nj)
          acc[mi][nj] = __builtin_amdgcn_mfma_f32_16x16x32_bf16(af[mi], bfr[nj], acc[mi][nj], 0, 0, 0);
    }
    __syncthreads();
  }

#pragma unroll
  for (int nj = 0; nj < 4; ++nj) {
    int col = n0 + wc * 64 + nj * 16 + fr;
    if (col < N) {
      float bv = bias[col];
#pragma unroll
      for (int mi = 0; mi < 4; ++mi) {
#pragma unroll
        for (int rg = 0; rg < 4; ++rg) {
          int row = m0 + wr * 64 + mi * 16 + fq * 4 + rg;
          float v = acc[mi][nj][rg] + bv;
          if (RELU) v = fmaxf(v, 0.f);
          if (OUTBF) ((short*)Cout)[(size_t)row * N + col] = f2bf(v);
          else       ((float*)Cout)[(size_t)row * N + col] = v;
        }
      }
    }
  }
}

// ==================== wide bf16 MFMA flash attention ====================
// block = (b,h,q-tile of 64); 4 waves, each 16 q-rows; KV tiles of 64.
__global__ __launch_bounds__(256) void k_attn(
    const short* __restrict__ qkvb,   // [4096][2304] bf16 (q|k|v)
    const short* __restrict__ vt,     // [768][4096] bf16
    const unsigned char* __restrict__ mask,
    short* __restrict__ ctxb)         // [4096][768] bf16
{
  __shared__ short KsS[64 * 192];      // row-major [kv][d], XOR-swizzled
  __shared__ short VtS[192 * 64];      // row-major [d][kv], XOR-swizzled
  __shared__ short PsS[4 * 16 * 72];   // per-wave P [16 q][72 shorts stride]
  __shared__ unsigned char MsB[64 * 64];

  int bid = blockIdx.x;
  int x   = bid & 7;
  int rest = bid >> 3;                 // 0..31
  int qt  = rest & 15;
  int bh  = x + 8 * (rest >> 4);       // 0..15
  int b = bh >> 2, h = bh & 3;
  int q0 = qt * 64;

  int t = threadIdx.x;
  int wq = t >> 6, l = t & 63;
  int fr = l & 15, fq = l >> 4;

  // Q fragments (A-operand), 6 d-chunks of 32
  bf16x8 qf[6];
#pragma unroll
  for (int dc = 0; dc < 6; ++dc)
    qf[dc] = *(const bf16x8*)&qkvb[(size_t)(b * SS + q0 + wq * 16 + fr) * 2304 + h * DQ + dc * 32 + fq * 8];

  f32x4 cacc[12];
#pragma unroll
  for (int i = 0; i < 12; ++i) cacc[i] = (f32x4){0.f, 0.f, 0.f, 0.f};
  float m_r[4] = {-INFINITY, -INFINITY, -INFINITY, -INFINITY};
  float l_r[4] = {0.f, 0.f, 0.f, 0.f};

  short* myPs = &PsS[wq * 1152];

  for (int kt = 0; kt < SS / 64; ++kt) {
    int kv0 = kt * 64;
    __syncthreads();
    // stage K [64][192] bf16: 1536 granules; swizzle source col ^ (row&7)
#pragma unroll
    for (int i = 0; i < 6; ++i) {
      int g = i * 256 + t;
      int kv = g / 24, cc = g % 24;
      int cs = cc ^ (kv & 7);
      const short* gp = &qkvb[(size_t)(b * SS + kv0 + kv) * 2304 + DD + h * DQ + cs * 8];
      __builtin_amdgcn_global_load_lds((const AS1 void*)gp, (AS3 void*)&KsS[g * 8], 16, 0, 0);
    }
    // stage Vt [192][64]: 1536 granules
#pragma unroll
    for (int i = 0; i < 6; ++i) {
      int g = i * 256 + t;
      int d = g >> 3, cc = g & 7;
      int cs = cc ^ (d & 7);
      const short* gp = &vt[(size_t)(h * DQ + d) * (BB * SS) + b * SS + kv0 + cs * 8];
      __builtin_amdgcn_global_load_lds((const AS1 void*)gp, (AS3 void*)&VtS[g * 8], 16, 0, 0);
    }
    // stage mask [64 q][64 kv] bytes
    {
      int q = t >> 2, c16 = t & 3;
      const unsigned char* gp = mask + (size_t)b * SS * SS + (size_t)(q0 + q) * SS + kv0 + c16 * 16;
      __builtin_amdgcn_global_load_lds((const AS1 void*)gp, (AS3 void*)&MsB[t * 16], 16, 0, 0);
    }
    __syncthreads();

    // ---- QK^T: S[16 q][64 kv] per wave ----
    f32x4 s[4];
#pragma unroll
    for (int nt = 0; nt < 4; ++nt) s[nt] = (f32x4){0.f, 0.f, 0.f, 0.f};
#pragma unroll
    for (int dc = 0; dc < 6; ++dc) {
#pragma unroll
      for (int nt = 0; nt < 4; ++nt) {
        int row = nt * 16 + fr;
        int wby = (dc * 64 + fq * 16) ^ ((fr & 7) << 4);
        bf16x8 kf = *(const bf16x8*)&KsS[row * 192 + (wby >> 1)];
        s[nt] = __builtin_amdgcn_mfma_f32_16x16x32_bf16(qf[dc], kf, s[nt], 0, 0, 0);
      }
    }

    // ---- online softmax (rows q = fq*4+reg, cols kv = nt*16+fr) ----
    float p[4][4];
    float mnew[4], alpha[4], psum[4];
#pragma unroll
    for (int rg = 0; rg < 4; ++rg) {
      float sv[4];
#pragma unroll
      for (int nt = 0; nt < 4; ++nt) {
        float v = s[nt][rg] * (1.f / 32.f);
        if (MsB[(fq * 4 + rg) * 64 + nt * 16 + fr]) v = -1e9f;
        sv[nt] = v;
      }
      float mx = fmaxf(fmaxf(sv[0], sv[1]), fmaxf(sv[2], sv[3]));
#pragma unroll
      for (int w2 = 1; w2 < 16; w2 <<= 1) mx = fmaxf(mx, __shfl_xor(mx, w2));
      mnew[rg] = fmaxf(m_r[rg], mx);
      alpha[rg] = expf(m_r[rg] - mnew[rg]);
      float ps = 0.f;
#pragma unroll
      for (int nt = 0; nt < 4; ++nt) {
        float pv = expf(sv[nt] - mnew[rg]);
        p[nt][rg] = pv;
        ps += pv;
      }
#pragma unroll
      for (int w2 = 1; w2 < 16; w2 <<= 1) ps += __shfl_xor(ps, w2);
      psum[rg] = ps;
      m_r[rg] = mnew[rg];
      l_r[rg] = l_r[rg] * alpha[rg] + ps;
    }
    // rescale ctx accumulators
#pragma unroll
    for (int nt = 0; nt < 12; ++nt)
#pragma unroll
      for (int rg = 0; rg < 4; ++rg)
        cacc[nt][rg] *= alpha[rg];

    // write P to per-wave LDS (bf16), stride 72 shorts
#pragma unroll
    for (int nt = 0; nt < 4; ++nt)
#pragma unroll
      for (int rg = 0; rg < 4; ++rg)
        myPs[(fq * 4 + rg) * 72 + nt * 16 + fr] = f2bf(p[nt][rg]);
    asm volatile("s_waitcnt lgkmcnt(0)" ::: "memory");

    // ---- PV: ctx[16 q][192 d] += P @ V ----
    bf16x8 pa[2];
#pragma unroll
    for (int kc = 0; kc < 2; ++kc)
      pa[kc] = *(const bf16x8*)&myPs[fr * 72 + kc * 32 + fq * 8];
#pragma unroll
    for (int nt = 0; nt < 12; ++nt) {
      int row = nt * 16 + fr;
#pragma unroll
      for (int kc = 0; kc < 2; ++kc) {
        int wby = (kc * 64 + fq * 16) ^ ((fr & 7) << 4);
        bf16x8 vf = *(const bf16x8*)&VtS[row * 64 + (wby >> 1)];
        cacc[nt] = __builtin_amdgcn_mfma_f32_16x16x32_bf16(pa[kc], vf, cacc[nt], 0, 0, 0);
      }
    }
  }

  // epilogue
#pragma unroll
  for (int nt = 0; nt < 12; ++nt) {
#pragma unroll
    for (int rg = 0; rg < 4; ++rg) {
      int row = b * SS + q0 + wq * 16 + fq * 4 + rg;
      ctxb[(size_t)row * DD + h * DQ + nt * 16 + fr] = f2bf(cacc[nt][rg] / l_r[rg]);
    }
  }
}

// ==================== narrow f32 path (cls accuracy) ====================
// q0f[4][768] = x0[4][768] @ Wq(+bq)
__global__ __launch_bounds__(256) void k_nq(
    const float* __restrict__ x0, const float* __restrict__ Wq,
    const float* __restrict__ bq, float* __restrict__ q0f)
{
  int idx = blockIdx.x * 256 + threadIdx.x;   // 3072 = 4 rows x 768 cols
  int cN = idx % DD, r = idx / DD;
  int h = cN / DQ, dq = cN % DQ;
  float acc = 0.f;
  for (int d = 0; d < DD; ++d)
    acc += x0[r * DD + d] * Wq[((size_t)h * DD + d) * DQ + dq];
  q0f[r * DD + cN] = acc + bq[cN];
}

// narrow attention: block = (b,h); f32 softmax over bf16 K,V
__global__ __launch_bounds__(256) void k_nattn(
    const float* __restrict__ q0f, const short* __restrict__ qkvb,
    const short* __restrict__ vt, const unsigned char* __restrict__ mask,
    float* __restrict__ ctx0)
{
  __shared__ float q0s[DQ];
  __shared__ float sc[SS];
  __shared__ float red[256];
  int blk = blockIdx.x;
  int b = blk >> 2, h = blk & 3;
  int t = threadIdx.x;
  if (t < DQ) q0s[t] = q0f[b * DD + h * DQ + t];
  __syncthreads();
#pragma unroll
  for (int i = 0; i < 4; ++i) {
    int kv = t + i * 256;
    const short* kp = &qkvb[(size_t)(b * SS + kv) * 2304 + DD + h * DQ];
    float s = 0.f;
    for (int d8 = 0; d8 < DQ / 8; ++d8) {
      bf16x8 kvv = *(const bf16x8*)&kp[d8 * 8];
#pragma unroll
      for (int j = 0; j < 8; ++j) s += q0s[d8 * 8 + j] * bf2f(kvv[j]);
    }
    s *= (1.f / 32.f);
    if (mask[(size_t)b * SS * SS + kv]) s = -1e9f;   // q-row 0
    sc[kv] = s;
  }
  __syncthreads();
  // block max
  float mx = fmaxf(fmaxf(sc[t], sc[t + 256]), fmaxf(sc[t + 512], sc[t + 768]));
  red[t] = mx;
  __syncthreads();
  for (int o = 128; o > 0; o >>= 1) { if (t < o) red[t] = fmaxf(red[t], red[t + o]); __syncthreads(); }
  float m = red[0];
  __syncthreads();
  float ls = 0.f;
#pragma unroll
  for (int i = 0; i < 4; ++i) {
    int kv = t + i * 256;
    float pv = expf(sc[kv] - m);
    sc[kv] = pv;
    ls += pv;
  }
  red[t] = ls;
  __syncthreads();
  for (int o = 128; o > 0; o >>= 1) { if (t < o) red[t] += red[t + o]; __syncthreads(); }
  float linv = 1.f / red[0];
  __syncthreads();
  if (t < DQ) {
    const short* vp = &vt[(size_t)(h * DQ + t) * (BB * SS) + b * SS];
    float acc = 0.f;
    for (int kv = 0; kv < SS; ++kv) acc += sc[kv] * bf2f(vp[kv]);
    ctx0[b * DD + h * DQ + t] = acc * linv;
  }
}

// small-M GEMM: C[4][N] = A[4][K] @ B[K][N] + bias  (B = original f32 weights)
template <int RELU>
__global__ __launch_bounds__(256) void k_nmm(
    const float* __restrict__ A, const float* __restrict__ B,
    const float* __restrict__ bias, float* __restrict__ C, int N, int K)
{
  extern __shared__ float As[];
  int t = threadIdx.x;
  for (int i = t; i < 4 * K; i += 256) As[i] = A[i];
  __syncthreads();
  int r = t >> 6, cN = blockIdx.x * 64 + (t & 63);
  float acc = 0.f;
  for (int k = 0; k < K; ++k) acc += As[r * K + k] * B[(size_t)k * N + cN];
  acc += bias[cN];
  if (RELU) acc = fmaxf(acc, 0.f);
  C[r * N + cN] = acc;
}

__global__ void k_cls(const float* __restrict__ ff0, const float* __restrict__ Wc,
                      const float* __restrict__ bc, float* __restrict__ out)
{
  int t = threadIdx.x;
  int o = t >> 3, l8 = t & 7;
  int b = o >> 1, cN = o & 1;
  float s = 0.f;
  for (int d = l8; d < DD; d += 8)
    s += ff0[b * DD + d] * Wc[d * 2 + cN];
#pragma unroll
  for (int w = 1; w < 8; w <<= 1) s += __shfl_xor(s, w);
  if (l8 == 0) out[o] = s + bc[cN];
}

// ==========================================================================
extern "C" void kernel_launch(void* const* d_in, const int* in_sizes, int n_in,
                              void* d_out, int out_size, void* d_ws, size_t ws_size,
                              hipStream_t stream)
{
  const int*           ids  = (const int*)d_in[0];
  const unsigned char* mask = (const unsigned char*)d_in[1];
  const float* tok  = (const float*)d_in[2];
  const float* seg  = (const float*)d_in[3];
  const float* pos  = (const float*)d_in[4];
  const float* ln_g = (const float*)d_in[5];
  const float* ln_b = (const float*)d_in[6];
  const float* Wq   = (const float*)d_in[7];
  const float* bq   = (const float*)d_in[8];
  const float* Wk   = (const float*)d_in[9];
  const float* bk   = (const float*)d_in[10];
  const float* Wv   = (const float*)d_in[11];
  const float* bv   = (const float*)d_in[12];
  const float* Wo   = (const float*)d_in[13];
  const float* bo   = (const float*)d_in[14];
  const float* W1   = (const float*)d_in[15];
  const float* b1   = (const float*)d_in[16];
  const float* W2   = (const float*)d_in[17];
  const float* b2   = (const float*)d_in[18];
  const float* Wtok = (const float*)d_in[19];
  const float* btok = (const float*)d_in[20];
  const float* Wcls = (const float*)d_in[21];
  const float* bcls = (const float*)d_in[22];

  // -------- workspace regions (float units), aliasing by lifetime --------
  float* ws = (float*)d_ws;
  // region0 [0 .. 11,747,328): qkvb -> {Bt1, ff1b} -> Btt
  short* qkvb = (short*)(ws);                          // [4096][2304] bf16
  short* Bt1  = (short*)(ws);                          // [3072][768]  bf16
  short* ff1b = (short*)(ws + 1310720);                // [4096][3072] bf16
  short* Btt  = (short*)(ws);                          // [30592][768] bf16
  // region1 [11,747,328 .. 13,320,192): vt -> Btwo -> Bt2
  short* vt   = (short*)(ws + 11747328);               // [768][4096] bf16
  short* Btwo = (short*)(ws + 11747328);               // [768][768]  bf16
  short* Bt2  = (short*)(ws + 11747328);               // [768][3072] bf16
  // region2 [13,320,192 .. 14,893,056): ctxb -> ffb
  short* ctxb = (short*)(ws + 13320192);               // [4096][768] bf16
  short* ffb  = (short*)(ws + 13320192);               // [4096][768] bf16
  // region3 [14,893,056 .. 16,465,920): xb -> attb
  short* xb   = (short*)(ws + 14893056);               // [4096][768] bf16
  short* attb = (short*)(ws + 14893056);               // [4096][768] bf16
  // region4 [16,465,920 .. 17,350,656): Btqkv -> narrow bufs
  short* Btqkv = (short*)(ws + 16465920);              // [2304][768] bf16
  float* q0f   = ws + 16465920;                        // [4][768]
  float* ctx0  = q0f + 3072;                           // [4][768]
  float* att0  = ctx0 + 3072;                          // [4][768]
  float* ff1_0 = att0 + 3072;                          // [4][3072]
  float* ff0   = ff1_0 + 12288;                        // [4][768]
  // region5 [17,350,656 ..): x0, bqkv
  float* x0   = ws + 17350656;                         // [4][768]
  float* bqkv = x0 + 3072;                             // [2304]

  float* cls    = (float*)d_out;
  float* tokout = (float*)d_out + 8;

  // 1. embeddings + LayerNorm
  k_embed_ln<<<BB * SS, 256, 0, stream>>>(ids, tok, seg, pos, ln_g, ln_b, xb, x0);

  // 2. QKV weight pack + bias pack
  k_packqkv<<<dim3(6, 24, 12), 256, 0, stream>>>(Wq, Wk, Wv, Btqkv);
  k_bpack<<<9, 256, 0, stream>>>(bq, bk, bv, bqkv);

  // 3. fused QKV GEMM -> qkvb bf16 [4096][2304]
  k_gemm_bf16<1, 0><<<8 * 4 * 18, 256, 0, stream>>>(xb, Btqkv, bqkv, qkvb, 2304, DD, 18);

  // 4. V transpose -> vt [768][4096]
  k_vtrans<<<dim3(128, 24), 256, 0, stream>>>(qkvb, vt);

  // 5-6. narrow q + narrow attention (needs qkvb, vt alive)
  k_nq<<<12, 256, 0, stream>>>(x0, Wq, bq, q0f);
  k_nattn<<<16, 256, 0, stream>>>(q0f, qkvb, vt, mask, ctx0);

  // 7. wide MFMA attention -> ctxb bf16
  k_attn<<<256, 256, 0, stream>>>(qkvb, vt, mask, ctxb);

  // narrow f32 chain (independent of wide GEMMs)
  k_nmm<0><<<12, 256, 4 * DD * 4, stream>>>(ctx0, Wo, bo, att0, DD, DD);
  k_nmm<1><<<48, 256, 4 * DD * 4, stream>>>(att0, W1, b1, ff1_0, DFF, DD);
  k_nmm<0><<<12, 256, 4 * DFF * 4, stream>>>(ff1_0, W2, b2, ff0, DD, DFF);
  k_cls<<<1, 64, 0, stream>>>(ff0, Wcls, bcls, cls);

  // 8. Wo GEMM -> attb
  k_wtrans<<<dim3(24, 24), 256, 0, stream>>>(Wo, Btwo, DD, DD);
  k_gemm_bf16<1, 0><<<8 * 4 * 6, 256, 0, stream>>>(ctxb, Btwo, bo, attb, DD, DD, 6);

  // 9. FFN
  k_wtrans<<<dim3(96, 24), 256, 0, stream>>>(W1, Bt1, DFF, DD);
  k_gemm_bf16<1, 1><<<8 * 4 * 24, 256, 0, stream>>>(attb, Bt1, b1, ff1b, DFF, DD, 24);
  k_wtrans<<<dim3(24, 96), 256, 0, stream>>>(W2, Bt2, DD, DFF);
  k_gemm_bf16<1, 0><<<8 * 4 * 6, 256, 0, stream>>>(ff1b, Bt2, b2, ffb, DD, DFF, 6);

  // 10. vocab projection (f32 out)
  k_wtrans<<<dim3(NPAD / 32, 24), 256, 0, stream>>>(Wtok, Btt, NVOC, DD);
  k_gemm_bf16<0, 0><<<8 * 4 * 239, 256, 0, stream>>>(ffb, Btt, btok, tokout, NVOC, DD, 239);
}

// Round 6
// 1230.337 us; speedup vs baseline: 3.6639x; 1.1174x over previous
//
#include <hip/hip_runtime.h>
#include <hip/hip_bf16.h>
#include <cstdint>
#include <cstddef>

#define BB   4
#define SS   1024
#define DD   768
#define HH   4
#define DQ   192
#define DFF  3072
#define NVOC 30522
#define NPAD 30592   // 239 * 128

typedef __attribute__((ext_vector_type(8))) short bf16x8;
typedef __attribute__((ext_vector_type(4))) float f32x4;
#define AS1 __attribute__((address_space(1)))
#define AS3 __attribute__((address_space(3)))

static __device__ __forceinline__ float bf2f(short s) {
  union { unsigned int u; float f; } v; v.u = ((unsigned int)(unsigned short)s) << 16; return v.f;
}
static __device__ __forceinline__ short f2bf(float f) {
  union { float f; unsigned int u; } v; v.f = f;
  unsigned int r = v.u + 0x7FFFu + ((v.u >> 16) & 1u);   // round-to-nearest-even
  if ((v.u & 0x7F800000u) == 0x7F800000u) r = v.u;       // inf/nan: truncate
  return (short)(r >> 16);
}

// ==================== embedding + LayerNorm -> xb (bf16), x0 (f32 rows s=0) ============
__global__ __launch_bounds__(256) void k_embed_ln(
    const int* __restrict__ ids, const float* __restrict__ tok,
    const float* __restrict__ seg, const float* __restrict__ pos,
    const float* __restrict__ g, const float* __restrict__ bta,
    short* __restrict__ xb, float* __restrict__ x0)
{
  int row = blockIdx.x;           // b*S + s
  int s = row & (SS - 1);
  int id = ids[row];
  int t = threadIdx.x;
  const float* tp = tok + (size_t)id * DD;
  const float* sp = seg + (size_t)id * DD;
  const float* pp = pos + (size_t)s * DD;
  float v[3];
  float sum = 0.f;
#pragma unroll
  for (int j = 0; j < 3; ++j) {
    int d = t + j * 256;
    v[j] = tp[d] + sp[d] + pp[d];
    sum += v[j];
  }
  __shared__ float red[4];
#pragma unroll
  for (int w = 1; w < 64; w <<= 1) sum += __shfl_xor(sum, w);
  int wid = t >> 6, lane = t & 63;
  if (lane == 0) red[wid] = sum;
  __syncthreads();
  float mu = (red[0] + red[1] + red[2] + red[3]) * (1.f / DD);
  float vs = 0.f;
#pragma unroll
  for (int j = 0; j < 3; ++j) { float d2 = v[j] - mu; vs += d2 * d2; }
#pragma unroll
  for (int w = 1; w < 64; w <<= 1) vs += __shfl_xor(vs, w);
  __syncthreads();
  if (lane == 0) red[wid] = vs;
  __syncthreads();
  float var = (red[0] + red[1] + red[2] + red[3]) * (1.f / DD);
  float rstd = rsqrtf(var + 1e-5f);
#pragma unroll
  for (int j = 0; j < 3; ++j) {
    int d = t + j * 256;
    float val = (v[j] - mu) * rstd * g[d] + bta[d];
    xb[(size_t)row * DD + d] = f2bf(val);
    if (s == 0) x0[(row >> 10) * DD + d] = val;
  }
}

// ==================== pack QKV weights -> Btqkv[2304][768] bf16 ====================
__global__ __launch_bounds__(256) void k_packqkv(
    const float* __restrict__ Wq, const float* __restrict__ Wk,
    const float* __restrict__ Wv, short* __restrict__ Bt)
{
  __shared__ float tile[32][33];
  int dq0 = blockIdx.x * 32;            // 0..160 within head
  int k0  = blockIdx.y * 32;
  int z   = blockIdx.z;                 // mat*4 + h
  int mat = z >> 2, h = z & 3;
  const float* W = mat == 0 ? Wq : (mat == 1 ? Wk : Wv);
  int tx = threadIdx.x & 31, ty = threadIdx.x >> 5;
#pragma unroll
  for (int j = 0; j < 4; ++j) {
    int kk = ty + j * 8;
    tile[kk][tx] = W[((size_t)h * DD + k0 + kk) * DQ + dq0 + tx];
  }
  __syncthreads();
#pragma unroll
  for (int j = 0; j < 4; ++j) {
    int r = ty + j * 8;                 // local dq
    Bt[(size_t)(mat * DD + h * DQ + dq0 + r) * DD + k0 + tx] = f2bf(tile[tx][r]);
  }
}

__global__ void k_bpack(const float* __restrict__ bq, const float* __restrict__ bk,
                        const float* __restrict__ bv, float* __restrict__ out)
{
  int t = blockIdx.x * 256 + threadIdx.x;
  if (t >= 3 * DD) return;
  out[t] = (t < DD) ? bq[t] : (t < 2 * DD ? bk[t - DD] : bv[t - 2 * DD]);
}

// ==================== generic f32[K][N] -> bf16 Bt[Npad][K] transpose ==============
__global__ __launch_bounds__(256) void k_wtrans(
    const float* __restrict__ W, short* __restrict__ Bt, int N, int K)
{
  __shared__ float tile[32][33];
  int n0 = blockIdx.x * 32, k0 = blockIdx.y * 32;
  int tx = threadIdx.x & 31, ty = threadIdx.x >> 5;
#pragma unroll
  for (int j = 0; j < 4; ++j) {
    int kk = ty + j * 8;
    tile[kk][tx] = (n0 + tx < N) ? W[(size_t)(k0 + kk) * N + n0 + tx] : 0.f;
  }
  __syncthreads();
#pragma unroll
  for (int j = 0; j < 4; ++j) {
    int r = ty + j * 8;
    Bt[(size_t)(n0 + r) * K + k0 + tx] = f2bf(tile[tx][r]);
  }
}

// ==================== V section of qkvb -> vt[768][4096] bf16 ======================
__global__ __launch_bounds__(256) void k_vtrans(
    const short* __restrict__ qkvb, short* __restrict__ vt)
{
  __shared__ short tile[32][33];
  int s0 = blockIdx.x * 32, d0 = blockIdx.y * 32;
  int tx = threadIdx.x & 31, ty = threadIdx.x >> 5;
#pragma unroll
  for (int j = 0; j < 4; ++j) {
    int kk = ty + j * 8;
    tile[kk][tx] = qkvb[(size_t)(s0 + kk) * 2304 + 2 * DD + d0 + tx];
  }
  __syncthreads();
#pragma unroll
  for (int j = 0; j < 4; ++j) {
    int r = ty + j * 8;
    vt[(size_t)(d0 + r) * (BB * SS) + s0 + tx] = tile[tx][r];
  }
}

// ==================== bf16 MFMA GEMM (M=4096), 128x128 tile, BK=64 =================
// T3-minimum double-buffer (stage t+1 before compute t, one barrier per K-step)
// + T2 both-sides XOR swizzle (source granule lc^lr, read slot ga^(row&7)).
template <int OUTBF, int RELU>
__global__ __launch_bounds__(256) void k_gemm_bf16(
    const short* __restrict__ A,    // [4096][K] bf16
    const short* __restrict__ Bt,   // [Ntiles*128][K] bf16 (row = output col)
    const float* __restrict__ bias, void* __restrict__ Cout,
    int N, int K, int NT)
{
  __shared__ alignas(16) short As[2][128 * 64];
  __shared__ alignas(16) short Bs[2][128 * 64];

  int bid = blockIdx.x;
  int xcd = bid & 7;
  int c   = bid >> 3;
  int tm  = xcd * 4 + (c & 3);  // 0..31
  int tn  = c >> 2;             // 0..NT-1
  int m0 = tm * 128, n0 = tn * 128;

  int t = threadIdx.x;
  int w = t >> 6, l = t & 63;
  int lr = l >> 3, lc = l & 7;
  int fr = l & 15, fq = l >> 4;
  int wr = w >> 1, wc = w & 1;

  // staging: linear LDS dest (wave-uniform base + lane*16), pre-swizzled SOURCE
  auto STAGE = [&](int buf, int k0) {
#pragma unroll
    for (int i = 0; i < 4; ++i) {
      int chunk = i * 4 + w;          // 0..15, wave-uniform
      int row = chunk * 8 + lr;       // 0..127 ; row&7 == lr
      int cs = lc ^ lr;               // swizzled 16B-granule within the row
      const short* gA = &A[(size_t)(m0 + row) * K + k0 + cs * 8];
      const short* gB = &Bt[(size_t)(n0 + row) * K + k0 + cs * 8];
      __builtin_amdgcn_global_load_lds((const AS1 void*)gA, (AS3 void*)&As[buf][chunk * 512], 16, 0, 0);
      __builtin_amdgcn_global_load_lds((const AS1 void*)gB, (AS3 void*)&Bs[buf][chunk * 512], 16, 0, 0);
    }
  };

  f32x4 acc[4][4];
#pragma unroll
  for (int i = 0; i < 4; ++i)
#pragma unroll
    for (int j = 0; j < 4; ++j)
      acc[i][j] = (f32x4){0.f, 0.f, 0.f, 0.f};

  int nk = K >> 6;
  STAGE(0, 0);
  __syncthreads();                    // buf0 ready
  int cur = 0;
  for (int kt = 0; kt < nk; ++kt) {
    if (kt + 1 < nk) STAGE(cur ^ 1, (kt + 1) * 64);   // in flight during compute
    const short* Acur = &As[cur][0];
    const short* Bcur = &Bs[cur][0];
#pragma unroll
    for (int ks = 0; ks < 2; ++ks) {
      bf16x8 af[4], bfr[4];
#pragma unroll
      for (int mi = 0; mi < 4; ++mi) {
        int row = wr * 64 + mi * 16 + fr;
        int slot = (ks * 4 + fq) ^ (fr & 7);          // swizzled read
        af[mi] = *(const bf16x8*)&Acur[row * 64 + slot * 8];
      }
#pragma unroll
      for (int nj = 0; nj < 4; ++nj) {
        int row = wc * 64 + nj * 16 + fr;
        int slot = (ks * 4 + fq) ^ (fr & 7);
        bfr[nj] = *(const bf16x8*)&Bcur[row * 64 + slot * 8];
      }
#pragma unroll
      for (int mi = 0; mi < 4; ++mi)
#pragma unroll
        for (int nj = 0; nj < 4; ++nj)
          acc[mi][nj] = __builtin_amdgcn_mfma_f32_16x16x32_bf16(af[mi], bfr[nj], acc[mi][nj], 0, 0, 0);
    }
    __syncthreads();                  // drains vmcnt (stage t+1 done) + all reads of cur done
    cur ^= 1;
  }

#pragma unroll
  for (int nj = 0; nj < 4; ++nj) {
    int col = n0 + wc * 64 + nj * 16 + fr;
    if (col < N) {
      float bv = bias[col];
#pragma unroll
      for (int mi = 0; mi < 4; ++mi) {
#pragma unroll
        for (int rg = 0; rg < 4; ++rg) {
          int row = m0 + wr * 64 + mi * 16 + fq * 4 + rg;
          float v = acc[mi][nj][rg] + bv;
          if (RELU) v = fmaxf(v, 0.f);
          if (OUTBF) ((short*)Cout)[(size_t)row * N + col] = f2bf(v);
          else       ((float*)Cout)[(size_t)row * N + col] = v;
        }
      }
    }
  }
}

// ==================== wide bf16 MFMA flash attention ====================
// block = (b,h,q-tile of 64); 4 waves, each 16 q-rows; KV tiles of 64.
__global__ __launch_bounds__(256) void k_attn(
    const short* __restrict__ qkvb,   // [4096][2304] bf16 (q|k|v)
    const short* __restrict__ vt,     // [768][4096] bf16
    const unsigned char* __restrict__ mask,
    short* __restrict__ ctxb)         // [4096][768] bf16
{
  __shared__ short KsS[64 * 192];      // row-major [kv][d], XOR-swizzled
  __shared__ short VtS[192 * 64];      // row-major [d][kv], XOR-swizzled
  __shared__ short PsS[4 * 16 * 72];   // per-wave P [16 q][72 shorts stride]
  __shared__ unsigned char MsB[64 * 64];

  int bid = blockIdx.x;
  int x   = bid & 7;
  int rest = bid >> 3;                 // 0..31
  int qt  = rest & 15;
  int bh  = x + 8 * (rest >> 4);       // 0..15
  int b = bh >> 2, h = bh & 3;
  int q0 = qt * 64;
  int t = threadIdx.x;
  int wq = t >> 6, l = t & 63;
  int fr = l & 15, fq = l >> 4;

  // Q fragments (A-operand), 6 d-chunks of 32
  bf16x8 qf[6];
#pragma unroll
  for (int dc = 0; dc < 6; ++dc)
    qf[dc] = *(const bf16x8*)&qkvb[(size_t)(b * SS + q0 + wq * 16 + fr) * 2304 + h * DQ + dc * 32 + fq * 8];

  f32x4 cacc[12];
#pragma unroll
  for (int i = 0; i < 12; ++i) cacc[i] = (f32x4){0.f, 0.f, 0.f, 0.f};
  float m_r[4] = {-INFINITY, -INFINITY, -INFINITY, -INFINITY};
  float l_r[4] = {0.f, 0.f, 0.f, 0.f};

  short* myPs = &PsS[wq * 1152];

  for (int kt = 0; kt < SS / 64; ++kt) {
    int kv0 = kt * 64;
    __syncthreads();
    // stage K [64][192] bf16: 1536 granules; swizzle source col ^ (row&7)
#pragma unroll
    for (int i = 0; i < 6; ++i) {
      int g = i * 256 + t;
      int kv = g / 24, cc = g % 24;
      int cs = cc ^ (kv & 7);
      const short* gp = &qkvb[(size_t)(b * SS + kv0 + kv) * 2304 + DD + h * DQ + cs * 8];
      __builtin_amdgcn_global_load_lds((const AS1 void*)gp, (AS3 void*)&KsS[g * 8], 16, 0, 0);
    }
    // stage Vt [192][64]: 1536 granules
#pragma unroll
    for (int i = 0; i < 6; ++i) {
      int g = i * 256 + t;
      int d = g >> 3, cc = g & 7;
      int cs = cc ^ (d & 7);
      const short* gp = &vt[(size_t)(h * DQ + d) * (BB * SS) + b * SS + kv0 + cs * 8];
      __builtin_amdgcn_global_load_lds((const AS1 void*)gp, (AS3 void*)&VtS[g * 8], 16, 0, 0);
    }
    // stage mask [64 q][64 kv] bytes
    {
      int q = t >> 2, c16 = t & 3;
      const unsigned char* gp = mask + (size_t)b * SS * SS + (size_t)(q0 + q) * SS + kv0 + c16 * 16;
      __builtin_amdgcn_global_load_lds((const AS1 void*)gp, (AS3 void*)&MsB[t * 16], 16, 0, 0);
    }
    __syncthreads();

    // ---- QK^T: S[16 q][64 kv] per wave ----
    f32x4 s[4];
#pragma unroll
    for (int nt = 0; nt < 4; ++nt) s[nt] = (f32x4){0.f, 0.f, 0.f, 0.f};
#pragma unroll
    for (int dc = 0; dc < 6; ++dc) {
#pragma unroll
      for (int nt = 0; nt < 4; ++nt) {
        int row = nt * 16 + fr;
        int wby = (dc * 64 + fq * 16) ^ ((fr & 7) << 4);
        bf16x8 kf = *(const bf16x8*)&KsS[row * 192 + (wby >> 1)];
        s[nt] = __builtin_amdgcn_mfma_f32_16x16x32_bf16(qf[dc], kf, s[nt], 0, 0, 0);
      }
    }

    // ---- online softmax (rows q = fq*4+reg, cols kv = nt*16+fr) ----
    float p[4][4];
    float mnew[4], alpha[4];
#pragma unroll
    for (int rg = 0; rg < 4; ++rg) {
      float sv[4];
#pragma unroll
      for (int nt = 0; nt < 4; ++nt) {
        float v = s[nt][rg] * (1.f / 32.f);
        if (MsB[(fq * 4 + rg) * 64 + nt * 16 + fr]) v = -1e9f;
        sv[nt] = v;
      }
      float mx = fmaxf(fmaxf(sv[0], sv[1]), fmaxf(sv[2], sv[3]));
#pragma unroll
      for (int w2 = 1; w2 < 16; w2 <<= 1) mx = fmaxf(mx, __shfl_xor(mx, w2));
      mnew[rg] = fmaxf(m_r[rg], mx);
      alpha[rg] = expf(m_r[rg] - mnew[rg]);
      float ps = 0.f;
#pragma unroll
      for (int nt = 0; nt < 4; ++nt) {
        float pv = expf(sv[nt] - mnew[rg]);
        p[nt][rg] = pv;
        ps += pv;
      }
#pragma unroll
      for (int w2 = 1; w2 < 16; w2 <<= 1) ps += __shfl_xor(ps, w2);
      m_r[rg] = mnew[rg];
      l_r[rg] = l_r[rg] * alpha[rg] + ps;
    }
    // rescale ctx accumulators
#pragma unroll
    for (int nt = 0; nt < 12; ++nt)
#pragma unroll
      for (int rg = 0; rg < 4; ++rg)
        cacc[nt][rg] *= alpha[rg];

    // write P to per-wave LDS (bf16), stride 72 shorts
#pragma unroll
    for (int nt = 0; nt < 4; ++nt)
#pragma unroll
      for (int rg = 0; rg < 4; ++rg)
        myPs[(fq * 4 + rg) * 72 + nt * 16 + fr] = f2bf(p[nt][rg]);
    asm volatile("s_waitcnt lgkmcnt(0)" ::: "memory");

    // ---- PV: ctx[16 q][192 d] += P @ V ----
    bf16x8 pa[2];
#pragma unroll
    for (int kc = 0; kc < 2; ++kc)
      pa[kc] = *(const bf16x8*)&myPs[fr * 72 + kc * 32 + fq * 8];
#pragma unroll
    for (int nt = 0; nt < 12; ++nt) {
      int row = nt * 16 + fr;
#pragma unroll
      for (int kc = 0; kc < 2; ++kc) {
        int wby = (kc * 64 + fq * 16) ^ ((fr & 7) << 4);
        bf16x8 vf = *(const bf16x8*)&VtS[row * 64 + (wby >> 1)];
        cacc[nt] = __builtin_amdgcn_mfma_f32_16x16x32_bf16(pa[kc], vf, cacc[nt], 0, 0, 0);
      }
    }
  }

  // epilogue
#pragma unroll
  for (int nt = 0; nt < 12; ++nt) {
#pragma unroll
    for (int rg = 0; rg < 4; ++rg) {
      int row = b * SS + q0 + wq * 16 + fq * 4 + rg;
      ctxb[(size_t)row * DD + h * DQ + nt * 16 + fr] = f2bf(cacc[nt][rg] / l_r[rg]);
    }
  }
}

// ==================== narrow f32 path (cls accuracy) ====================
// q0f[4][768] = x0[4][768] @ Wq(+bq); 4-way K-sliced for latency
__global__ __launch_bounds__(256) void k_nq(
    const float* __restrict__ x0, const float* __restrict__ Wq,
    const float* __restrict__ bq, float* __restrict__ q0f)
{
  __shared__ float x0s[4 * DD];
  __shared__ float red[4][4][64];
  int t = threadIdx.x;
  for (int i = t; i < 4 * DD; i += 256) x0s[i] = x0[i];
  __syncthreads();
  int cl = t & 63, ks = t >> 6;
  int cN = blockIdx.x * 64 + cl;        // 0..767
  int h = cN / DQ, dq = cN % DQ;
  float acc[4] = {0.f, 0.f, 0.f, 0.f};
  for (int d = ks * 192; d < ks * 192 + 192; ++d) {
    float wv = Wq[((size_t)h * DD + d) * DQ + dq];
#pragma unroll
    for (int r = 0; r < 4; ++r) acc[r] += x0s[r * DD + d] * wv;
  }
#pragma unroll
  for (int r = 0; r < 4; ++r) red[ks][r][cl] = acc[r];
  __syncthreads();
  if (ks == 0) {
#pragma unroll
    for (int r = 0; r < 4; ++r)
      q0f[r * DD + cN] = red[0][r][cl] + red[1][r][cl] + red[2][r][cl] + red[3][r][cl] + bq[cN];
  }
}

// narrow attention: block = (b,h); f32 softmax over bf16 K,V
__global__ __launch_bounds__(256) void k_nattn(
    const float* __restrict__ q0f, const short* __restrict__ qkvb,
    const short* __restrict__ vt, const unsigned char* __restrict__ mask,
    float* __restrict__ ctx0)
{
  __shared__ float q0s[DQ];
  __shared__ float sc[SS];
  __shared__ float red[256];
  int blk = blockIdx.x;
  int b = blk >> 2, h = blk & 3;
  int t = threadIdx.x;
  if (t < DQ) q0s[t] = q0f[b * DD + h * DQ + t];
  __syncthreads();
#pragma unroll
  for (int i = 0; i < 4; ++i) {
    int kv = t + i * 256;
    const short* kp = &qkvb[(size_t)(b * SS + kv) * 2304 + DD + h * DQ];
    float s = 0.f;
    for (int d8 = 0; d8 < DQ / 8; ++d8) {
      bf16x8 kvv = *(const bf16x8*)&kp[d8 * 8];
#pragma unroll
      for (int j = 0; j < 8; ++j) s += q0s[d8 * 8 + j] * bf2f(kvv[j]);
    }
    s *= (1.f / 32.f);
    if (mask[(size_t)b * SS * SS + kv]) s = -1e9f;   // q-row 0
    sc[kv] = s;
  }
  __syncthreads();
  float mx = fmaxf(fmaxf(sc[t], sc[t + 256]), fmaxf(sc[t + 512], sc[t + 768]));
  red[t] = mx;
  __syncthreads();
  for (int o = 128; o > 0; o >>= 1) { if (t < o) red[t] = fmaxf(red[t], red[t + o]); __syncthreads(); }
  float m = red[0];
  __syncthreads();
  float ls = 0.f;
#pragma unroll
  for (int i = 0; i < 4; ++i) {
    int kv = t + i * 256;
    float pv = expf(sc[kv] - m);
    sc[kv] = pv;
    ls += pv;
  }
  red[t] = ls;
  __syncthreads();
  for (int o = 128; o > 0; o >>= 1) { if (t < o) red[t] += red[t + o]; __syncthreads(); }
  float linv = 1.f / red[0];
  __syncthreads();
  if (t < DQ) {
    const short* vp = &vt[(size_t)(h * DQ + t) * (BB * SS) + b * SS];
    float acc = 0.f;
    for (int kv = 0; kv < SS; ++kv) acc += sc[kv] * bf2f(vp[kv]);
    ctx0[b * DD + h * DQ + t] = acc * linv;
  }
}

// small-M GEMM: C[4][N] = A[4][K] @ B[K][N] + bias; 4-way K-sliced
template <int RELU>
__global__ __launch_bounds__(256) void k_nmm(
    const float* __restrict__ A, const float* __restrict__ B,
    const float* __restrict__ bias, float* __restrict__ C, int N, int K)
{
  extern __shared__ float As[];          // 4*K floats + 1024 floats reduce
  float* red = As + 4 * K;               // [4 ks][4 r][64 c]
  int t = threadIdx.x;
  for (int i = t; i < 4 * K; i += 256) As[i] = A[i];
  __syncthreads();
  int cl = t & 63, ks = t >> 6;
  int cN = blockIdx.x * 64 + cl;
  int kq = K >> 2;
  float acc[4] = {0.f, 0.f, 0.f, 0.f};
  for (int k = ks * kq; k < ks * kq + kq; ++k) {
    float bvv = B[(size_t)k * N + cN];
#pragma unroll
    for (int r = 0; r < 4; ++r) acc[r] += As[r * K + k] * bvv;
  }
#pragma unroll
  for (int r = 0; r < 4; ++r) red[(ks * 4 + r) * 64 + cl] = acc[r];
  __syncthreads();
  if (ks == 0) {
#pragma unroll
    for (int r = 0; r < 4; ++r) {
      float v = red[(0 + r) * 64 + cl] + red[(4 + r) * 64 + cl] +
                red[(8 + r) * 64 + cl] + red[(12 + r) * 64 + cl] + bias[cN];
      if (RELU) v = fmaxf(v, 0.f);
      C[r * N + cN] = v;
    }
  }
}

__global__ void k_cls(const float* __restrict__ ff0, const float* __restrict__ Wc,
                      const float* __restrict__ bc, float* __restrict__ out)
{
  int t = threadIdx.x;
  int o = t >> 3, l8 = t & 7;
  int b = o >> 1, cN = o & 1;
  float s = 0.f;
  for (int d = l8; d < DD; d += 8)
    s += ff0[b * DD + d] * Wc[d * 2 + cN];
#pragma unroll
  for (int w = 1; w < 8; w <<= 1) s += __shfl_xor(s, w);
  if (l8 == 0) out[o] = s + bc[cN];
}

// ==========================================================================
extern "C" void kernel_launch(void* const* d_in, const int* in_sizes, int n_in,
                              void* d_out, int out_size, void* d_ws, size_t ws_size,
                              hipStream_t stream)
{
  const int*           ids  = (const int*)d_in[0];
  const unsigned char* mask = (const unsigned char*)d_in[1];
  const float* tok  = (const float*)d_in[2];
  const float* seg  = (const float*)d_in[3];
  const float* pos  = (const float*)d_in[4];
  const float* ln_g = (const float*)d_in[5];
  const float* ln_b = (const float*)d_in[6];
  const float* Wq   = (const float*)d_in[7];
  const float* bq   = (const float*)d_in[8];
  const float* Wk   = (const float*)d_in[9];
  const float* bk   = (const float*)d_in[10];
  const float* Wv   = (const float*)d_in[11];
  const float* bv   = (const float*)d_in[12];
  const float* Wo   = (const float*)d_in[13];
  const float* bo   = (const float*)d_in[14];
  const float* W1   = (const float*)d_in[15];
  const float* b1   = (const float*)d_in[16];
  const float* W2   = (const float*)d_in[17];
  const float* b2   = (const float*)d_in[18];
  const float* Wtok = (const float*)d_in[19];
  const float* btok = (const float*)d_in[20];
  const float* Wcls = (const float*)d_in[21];
  const float* bcls = (const float*)d_in[22];

  // -------- workspace regions (float units), aliasing by lifetime --------
  float* ws = (float*)d_ws;
  short* qkvb = (short*)(ws);                          // [4096][2304] bf16
  short* Bt1  = (short*)(ws);                          // [3072][768]  bf16
  short* ff1b = (short*)(ws + 1310720);                // [4096][3072] bf16
  short* Btt  = (short*)(ws);                          // [30592][768] bf16
  short* vt   = (short*)(ws + 11747328);               // [768][4096] bf16
  short* Btwo = (short*)(ws + 11747328);               // [768][768]  bf16
  short* Bt2  = (short*)(ws + 11747328);               // [768][3072] bf16
  short* ctxb = (short*)(ws + 13320192);               // [4096][768] bf16
  short* ffb  = (short*)(ws + 13320192);               // [4096][768] bf16
  short* xb   = (short*)(ws + 14893056);               // [4096][768] bf16
  short* attb = (short*)(ws + 14893056);               // [4096][768] bf16
  short* Btqkv = (short*)(ws + 16465920);              // [2304][768] bf16
  float* q0f   = ws + 16465920;                        // [4][768] (after Btqkv dead? no - after QKV GEMM)
  float* ctx0  = q0f + 3072;
  float* att0  = ctx0 + 3072;
  float* ff1_0 = att0 + 3072;
  float* ff0   = ff1_0 + 12288;
  float* x0   = ws + 17350656;
  float* bqkv = x0 + 3072;

  float* cls    = (float*)d_out;
  float* tokout = (float*)d_out + 8;

  // 1. embeddings + LayerNorm
  k_embed_ln<<<BB * SS, 256, 0, stream>>>(ids, tok, seg, pos, ln_g, ln_b, xb, x0);

  // 2. QKV weight pack + bias pack
  k_packqkv<<<dim3(6, 24, 12), 256, 0, stream>>>(Wq, Wk, Wv, Btqkv);
  k_bpack<<<9, 256, 0, stream>>>(bq, bk, bv, bqkv);

  // 3. fused QKV GEMM -> qkvb bf16 [4096][2304]
  k_gemm_bf16<1, 0><<<8 * 4 * 18, 256, 0, stream>>>(xb, Btqkv, bqkv, qkvb, 2304, DD, 18);

  // 4. V transpose -> vt [768][4096]
  k_vtrans<<<dim3(128, 24), 256, 0, stream>>>(qkvb, vt);

  // 5-6. narrow q + narrow attention (needs qkvb, vt alive; q0f aliases Btqkv which is now dead)
  k_nq<<<12, 256, 0, stream>>>(x0, Wq, bq, q0f);
  k_nattn<<<16, 256, 0, stream>>>(q0f, qkvb, vt, mask, ctx0);

  // 7. wide MFMA attention -> ctxb bf16
  k_attn<<<256, 256, 0, stream>>>(qkvb, vt, mask, ctxb);

  // narrow f32 chain
  k_nmm<0><<<12, 256, (4 * DD + 1024) * 4, stream>>>(ctx0, Wo, bo, att0, DD, DD);
  k_nmm<1><<<48, 256, (4 * DD + 1024) * 4, stream>>>(att0, W1, b1, ff1_0, DFF, DD);
  k_nmm<0><<<12, 256, (4 * DFF + 1024) * 4, stream>>>(ff1_0, W2, b2, ff0, DD, DFF);
  k_cls<<<1, 64, 0, stream>>>(ff0, Wcls, bcls, cls);

  // 8. Wo GEMM -> attb
  k_wtrans<<<dim3(24, 24), 256, 0, stream>>>(Wo, Btwo, DD, DD);
  k_gemm_bf16<1, 0><<<8 * 4 * 6, 256, 0, stream>>>(ctxb, Btwo, bo, attb, DD, DD, 6);

  // 9. FFN
  k_wtrans<<<dim3(96, 24), 256, 0, stream>>>(W1, Bt1, DFF, DD);
  k_gemm_bf16<1, 1><<<8 * 4 * 24, 256, 0, stream>>>(attb, Bt1, b1, ff1b, DFF, DD, 24);
  k_wtrans<<<dim3(24, 96), 256, 0, stream>>>(W2, Bt2, DD, DFF);
  k_gemm_bf16<1, 0><<<8 * 4 * 6, 256, 0, stream>>>(ff1b, Bt2, b2, ffb, DD, DFF, 6);

  // 10. vocab projection (f32 out)
  k_wtrans<<<dim3(NPAD / 32, 24), 256, 0, stream>>>(Wtok, Btt, NVOC, DD);
  k_gemm_bf16<0, 0><<<8 * 4 * 239, 256, 0, stream>>>(ffb, Btt, btok, tokout, NVOC, DD, 239);
}